// Round 4
// baseline (175.159 us; speedup 1.0000x reference)
//
#include <hip/hip_runtime.h>

// Flatten 2x2 blocks, fp32:
//   out[plane + i*1024 + 4j + 2r + s] = x[plane + (2i+r)*512 + 2j + s]
//
// Pair form (each lane owns TWO consecutive output float4s):
//   pair index P, I = P>>7, j = P&127:
//     A = x4[I*256 + j]        (row 2i,   16B dense across lanes)
//     B = x4[I*256 + 128 + j]  (row 2i+1, 16B dense across lanes)
//     out4[2P]   = {A.x, A.y, B.x, B.y}
//     out4[2P+1] = {A.z, A.w, B.z, B.w}
// Loads are now FULL-WIDTH dwordx4 (1KB/wave-instr) — matching the 6.3 TB/s
// copy ubench's access shape. Stores are 2x dwordx4 at 32B lane stride
// (half-density — shown free in earlier rounds; L2 merges half-lines).
//
// Nontemporal on BOTH sides retained (round-3's only effective lever, -20%:
// no cache allocation -> no forced evictions of the harness's poison-dirty
// L3 lines). No LDS, no barriers, register-local merge.

namespace {
constexpr int UNROLL = 4;    // pairs per lane
constexpr int BLOCKS = 3072;
// total pairs = BLOCKS * 4 waves * UNROLL * 64 lanes = 3,145,728
//             = 25,165,824 floats / 8 floats-per-pair  ✓ exact cover
}

typedef float fx4 __attribute__((ext_vector_type(4)));

__global__ __launch_bounds__(256) void flatten2x2_x4nt(const float* __restrict__ x,
                                                       float* __restrict__ out) {
    const int tid  = (int)threadIdx.x;
    const int w    = tid >> 6;   // wave 0..3
    const int lane = tid & 63;

    const fx4* __restrict__ x4 = (const fx4*)x;
    fx4* __restrict__ o4       = (fx4*)out;

    const int p0 = (((int)blockIdx.x * 4 + w) * UNROLL) * 64 + lane;

    fx4 A[UNROLL], B[UNROLL];
    // --- 8 independent full-width NT loads, 1KB/wave-instr, dense ---
#pragma unroll
    for (int u = 0; u < UNROLL; ++u) {
        const int P = p0 + u * 64;
        const int I = P >> 7;          // global superrow
        const int j = P & 127;         // float4-pair column
        A[u] = __builtin_nontemporal_load(&x4[(I << 8) + j]);        // row 2i
        B[u] = __builtin_nontemporal_load(&x4[(I << 8) + 128 + j]);  // row 2i+1
    }
    // --- register merge, 2x dwordx4 NT stores per pair ---
#pragma unroll
    for (int u = 0; u < UNROLL; ++u) {
        const int P = p0 + u * 64;
        fx4 lo, hi;
        lo.x = A[u].x; lo.y = A[u].y; lo.z = B[u].x; lo.w = B[u].y;
        hi.x = A[u].z; hi.y = A[u].w; hi.z = B[u].z; hi.w = B[u].w;
        __builtin_nontemporal_store(lo, &o4[2 * P]);
        __builtin_nontemporal_store(hi, &o4[2 * P + 1]);
    }
}

extern "C" void kernel_launch(void* const* d_in, const int* in_sizes, int n_in,
                              void* d_out, int out_size, void* d_ws, size_t ws_size,
                              hipStream_t stream) {
    const float* x = (const float*)d_in[0];
    float* out = (float*)d_out;
    flatten2x2_x4nt<<<BLOCKS, 256, 0, stream>>>(x, out);
}

// Round 5
// 169.215 us; speedup vs baseline: 1.0351x; 1.0351x over previous
//
#include <hip/hip_runtime.h>

// Flatten 2x2 blocks, fp32:
//   out[plane + i*1024 + 4j + 2r + s] = x[plane + (2i+r)*512 + 2j + s]
//
// Superrow identity: output superrow S (1024 floats at out[S*1024]) is a
// self-contained permutation of input floats [S*1024, S*1024+1024)
// (= input rows 2i, 2i+1):  out4[S*256 + k] = { x2[S*512 + k], x2[S*512 + 256 + k] }
//
// Round-8 design: R3 (dense dwordx2 NT loads + dense dwordx4 NT stores, no
// LDS) = ~50 us, the best point.  R4 proved strided NT stores cost +10 us
// (NT bypasses L2 merge -> 32B partial-line writes).  The ONLY remaining
// shape difference vs the 6.3 TB/s copy ubench is load width (x2 vs x4).
// Dense-x4-loads + dense-stores requires cross-lane movement, so: stage each
// wave's superrow through wave-PRIVATE LDS (no __syncthreads — a wave only
// reads what it wrote; compiler's lgkmcnt ordering suffices).
//   stage: 4x global_load_dwordx4 (NT, dense 1KB/instr) -> ds_write_b128 dense
//   emit:  2x ds_read_b64 (2 lanes/bank = free) -> dwordx4 NT store (dense)
// NT retained on BOTH global sides (round-3's -20%: no allocation -> no
// forced eviction of the harness's poison-dirty L3 lines).

namespace {
constexpr int ITERS  = 2;
constexpr int BLOCKS = 3072;   // BLOCKS * 4 waves * ITERS = 24576 superrows ✓
}

typedef float fx2 __attribute__((ext_vector_type(2)));
typedef float fx4 __attribute__((ext_vector_type(4)));

__global__ __launch_bounds__(256) void flatten2x2_ldsnt(const float* __restrict__ x,
                                                        float* __restrict__ out) {
    __shared__ float lds[4 * 1024];   // 16 KB: one 4KB superrow buffer per wave

    const int tid  = (int)threadIdx.x;
    const int w    = tid >> 6;   // wave 0..3
    const int lane = tid & 63;

    const fx4* __restrict__ x4 = (const fx4*)x;
    fx4* __restrict__ o4       = (fx4*)out;

    float* const myl       = lds + w * 1024;   // wave-private
    fx4* const myl4        = (fx4*)myl;
    const fx2* const myl2  = (const fx2*)myl;

    for (int t = 0; t < ITERS; ++t) {
        const int S = ((int)blockIdx.x * 4 + w) * ITERS + t;   // superrow id
        const fx4* __restrict__ src = x4 + S * 256;
        fx4* __restrict__ dst       = o4 + S * 256;

        // --- stage: 4 full-width NT loads (dense), then dense b128 LDS writes
        fx4 v[4];
#pragma unroll
        for (int m = 0; m < 4; ++m)
            v[m] = __builtin_nontemporal_load(&src[m * 64 + lane]);
#pragma unroll
        for (int m = 0; m < 4; ++m)
            myl4[m * 64 + lane] = v[m];

        // --- emit: f2 pair reads (conflict-free), dense x4 NT stores
#pragma unroll
        for (int m = 0; m < 4; ++m) {
            const int k = m * 64 + lane;
            const fx2 a = myl2[k];         // row 2i
            const fx2 b = myl2[256 + k];   // row 2i+1
            fx4 o;
            o.x = a.x; o.y = a.y; o.z = b.x; o.w = b.y;
            __builtin_nontemporal_store(o, &dst[k]);
        }
    }
}

extern "C" void kernel_launch(void* const* d_in, const int* in_sizes, int n_in,
                              void* d_out, int out_size, void* d_ws, size_t ws_size,
                              hipStream_t stream) {
    const float* x = (const float*)d_in[0];
    float* out = (float*)d_out;
    flatten2x2_ldsnt<<<BLOCKS, 256, 0, stream>>>(x, out);
}

// Round 6
// 166.245 us; speedup vs baseline: 1.0536x; 1.0179x over previous
//
#include <hip/hip_runtime.h>

// Flatten 2x2 blocks, fp32:
//   out[plane + i*1024 + 4j + 2r + s] = x[plane + (2i+r)*512 + 2j + s]
//
// FINAL (revert to round-3 kernel — session minimum, 165.06 us bench,
// kernel ~50 us ~= 4.0 TB/s logical).
//
// Identity (float2/float4 view): with output-float4 index g, I = g>>8, k = g&255:
//   out4[g] = { x2[I*512 + k], x2[I*512 + 256 + k] }
// Both global sides dense, merge register-local. No LDS, no barriers.
//
// Six-round ablation ledger:
//   nontemporal both sides : -20%  (ONLY mover; no cache allocation -> no
//                                   forced eviction of poison-dirty L3 lines)
//   store density under NT : mandatory (strided NT stores +10 us — NT bypasses
//                                   L2 half-line merge)
//   load width x2->x4      : null  (via wave-private LDS stage, R5)
//   LDS staging            : null/negative
//   MLP depth, sync, occupancy, persistence : all null
// Residual gap to 6.3 TB/s copy ceiling = harness poison-fill L3 writeback
// drain (~250 MB) sharing HBM write path with the kernel. Harness-conditioned
// roofline.

namespace {
constexpr int UNROLL = 8;    // chunks (64 output float4s each) per wave
constexpr int BLOCKS = 3072; // x 4 waves x UNROLL chunks = 98304 = exact cover
}

typedef float fx2 __attribute__((ext_vector_type(2)));
typedef float fx4 __attribute__((ext_vector_type(4)));

__global__ __launch_bounds__(256) void flatten2x2_nt(const float* __restrict__ x,
                                                     float* __restrict__ out) {
    const int tid  = (int)threadIdx.x;
    const int w    = tid >> 6;   // wave 0..3
    const int lane = tid & 63;

    const fx2* __restrict__ x2 = (const fx2*)x;
    fx4* __restrict__ o4       = (fx4*)out;

    const int chunk0 = (int)blockIdx.x * (4 * UNROLL) + w * UNROLL;

    fx2 a[UNROLL], b[UNROLL];
    // --- 16 independent nontemporal loads, dense 512B/instr ---
#pragma unroll
    for (int u = 0; u < UNROLL; ++u) {
        const int g  = (chunk0 + u) * 64 + lane;   // output float4 index
        const int f2 = g + ((g >> 8) << 8);        // = (g>>8)*512 + (g&255)
        a[u] = __builtin_nontemporal_load(&x2[f2]);        // row 2i
        b[u] = __builtin_nontemporal_load(&x2[f2 + 256]);  // row 2i+1
    }
    // --- register merge, dense nontemporal stores 1KB/instr ---
#pragma unroll
    for (int u = 0; u < UNROLL; ++u) {
        const int g = (chunk0 + u) * 64 + lane;
        fx4 v;
        v.x = a[u].x; v.y = a[u].y; v.z = b[u].x; v.w = b[u].y;
        __builtin_nontemporal_store(v, &o4[g]);
    }
}

extern "C" void kernel_launch(void* const* d_in, const int* in_sizes, int n_in,
                              void* d_out, int out_size, void* d_ws, size_t ws_size,
                              hipStream_t stream) {
    const float* x = (const float*)d_in[0];
    float* out = (float*)d_out;
    flatten2x2_nt<<<BLOCKS, 256, 0, stream>>>(x, out);
}